// Round 13
// baseline (333.822 us; speedup 1.0000x reference)
//
#include <hip/hip_runtime.h>
#include <hip/hip_fp16.h>
#include <math.h>

#define FIN 78
#define HD1 512
#define D2  128
#define KP1 40   // layer-1 k-pairs (78 padded to 80)

typedef _Float16 f16x2 __attribute__((ext_vector_type(2)));
union U2H { unsigned u; f16x2 h; __half2 hh; };
__device__ __forceinline__ f16x2 u2h(unsigned u) { U2H x; x.u = u; return x.h; }
union V16 { uint4 u4; f16x2 h[4]; };

__device__ __forceinline__ float elu(float x) { return x > 0.f ? x : expf(x) - 1.f; }

// ---------- W pack: W1 [78][512]x2 -> Wt1[1024][40] ; W2 [512][128]x2 -> Wt2[256][256] ----------
__global__ void cvtW_k(const float* __restrict__ Wl1, const float* __restrict__ Wr1,
                       const float* __restrict__ Wl2, const float* __restrict__ Wr2,
                       unsigned* __restrict__ Wt1, unsigned* __restrict__ Wt2)
{
    int idx = blockIdx.x * 256 + threadIdx.x;
    if (idx < 1024 * KP1) {
        int col = idx / KP1, k2 = idx - col * KP1;
        const float* W = (col < HD1) ? Wl1 : Wr1;
        int c = (col < HD1) ? col : col - HD1;
        float w0 = (2 * k2     < FIN) ? W[(2 * k2)     * HD1 + c] : 0.f;
        float w1 = (2 * k2 + 1 < FIN) ? W[(2 * k2 + 1) * HD1 + c] : 0.f;
        U2H x; x.h = (f16x2){(_Float16)w0, (_Float16)w1};
        Wt1[idx] = x.u;
    } else if (idx < 1024 * KP1 + 256 * 256) {
        int j = idx - 1024 * KP1;
        int col = j >> 8, k2 = j & 255;
        const float* W = (col < D2) ? Wl2 : Wr2;
        int c = (col < D2) ? col : col - D2;
        float w0 = W[(2 * k2) * D2 + c], w1 = W[(2 * k2 + 1) * D2 + c];
        U2H x; x.h = (f16x2){(_Float16)w0, (_Float16)w1};
        Wt2[j] = x.u;
    }
}

// ---------- layer-1 GEMM via fdot2: x[N,78] @ Wt1 -> xl,xr fp16 ----------
// block: 16 rows x 1024 cols; thread: 16 rows x 4 cols.
__global__ __launch_bounds__(256, 4)
void gemm1_k(const float* __restrict__ x, const unsigned* __restrict__ Wt1,
             const float* __restrict__ bl, const float* __restrict__ br,
             __half* __restrict__ xl, __half* __restrict__ xr, int N)
{
    __shared__ unsigned hs[16][KP1];
    int row0 = blockIdx.x * 16;
    int t = threadIdx.x;
    for (int idx = t; idx < 16 * KP1; idx += 256) {
        int r = idx / KP1, k2 = idx - r * KP1;
        int row = row0 + r;
        float lo = 0.f, hi = 0.f;
        if (row < N) {
            lo = (2 * k2     < FIN) ? x[(size_t)row * FIN + 2 * k2]     : 0.f;
            hi = (2 * k2 + 1 < FIN) ? x[(size_t)row * FIN + 2 * k2 + 1] : 0.f;
        }
        U2H p; p.h = (f16x2){(_Float16)lo, (_Float16)hi};
        hs[r][k2] = p.u;
    }
    __syncthreads();

    const unsigned* wp0 = Wt1 + (size_t)(t      ) * KP1;
    const unsigned* wp1 = Wt1 + (size_t)(t + 256) * KP1;
    const unsigned* wp2 = Wt1 + (size_t)(t + 512) * KP1;
    const unsigned* wp3 = Wt1 + (size_t)(t + 768) * KP1;
    float acc[16][4];
#pragma unroll
    for (int r = 0; r < 16; ++r)
        { acc[r][0]=0.f; acc[r][1]=0.f; acc[r][2]=0.f; acc[r][3]=0.f; }

    for (int k2 = 0; k2 < KP1; ++k2) {
        unsigned w0 = wp0[k2], w1 = wp1[k2], w2 = wp2[k2], w3 = wp3[k2];
#pragma unroll
        for (int r = 0; r < 16; ++r) {
            f16x2 xv = u2h(hs[r][k2]);
            acc[r][0] = __builtin_amdgcn_fdot2(xv, u2h(w0), acc[r][0], false);
            acc[r][1] = __builtin_amdgcn_fdot2(xv, u2h(w1), acc[r][1], false);
            acc[r][2] = __builtin_amdgcn_fdot2(xv, u2h(w2), acc[r][2], false);
            acc[r][3] = __builtin_amdgcn_fdot2(xv, u2h(w3), acc[r][3], false);
        }
    }

#pragma unroll
    for (int i = 0; i < 4; ++i) {
        int j = t + i * 256;
        bool isL = j < HD1;
        int col = isL ? j : j - HD1;
        float b = isL ? bl[col] : br[col];
        __half* outp = isL ? xl : xr;
        for (int r = 0; r < 16; ++r) {
            int row = row0 + r;
            if (row < N) outp[(size_t)row * HD1 + col] = __float2half(acc[r][i] + b);
        }
    }
}

// ---------- layer-2 GEMM via fdot2: h1[N,512]f16 @ Wt2 -> xl2,xr2 fp16 ----------
__global__ __launch_bounds__(256, 4)
void gemm2_k(const __half* __restrict__ h, const unsigned* __restrict__ Wt,
             const float* __restrict__ bl, const float* __restrict__ br,
             __half* __restrict__ xl, __half* __restrict__ xr, int N)
{
    __shared__ unsigned hs[16][256];
    int row0 = blockIdx.x * 16;
    int t = threadIdx.x;
    for (int idx = t; idx < 16 * 64; idx += 256) {
        int r = idx >> 6, q = idx & 63;
        int row = row0 + r;
        uint4 val = make_uint4(0u, 0u, 0u, 0u);
        if (row < N) val = *(const uint4*)(h + (size_t)row * HD1 + q * 8);
        *(uint4*)&hs[r][q * 4] = val;
    }
    __syncthreads();

    int c = t & 127, rg = t >> 7;                // cols 2c,2c+1; rows rg*8..rg*8+7
    const unsigned* w0p = Wt + (size_t)(2 * c)     * 256;
    const unsigned* w1p = Wt + (size_t)(2 * c + 1) * 256;
    float acc[8][2];
#pragma unroll
    for (int r = 0; r < 8; ++r) { acc[r][0] = 0.f; acc[r][1] = 0.f; }

    for (int k2 = 0; k2 < 256; ++k2) {
        f16x2 w0 = u2h(w0p[k2]);
        f16x2 w1 = u2h(w1p[k2]);
#pragma unroll
        for (int r = 0; r < 8; ++r) {
            f16x2 hv = u2h(hs[rg * 8 + r][k2]);
            acc[r][0] = __builtin_amdgcn_fdot2(hv, w0, acc[r][0], false);
            acc[r][1] = __builtin_amdgcn_fdot2(hv, w1, acc[r][1], false);
        }
    }

    if (c < 64) {
        int cc = 2 * c;
        float b0 = bl[cc], b1 = bl[cc + 1];
#pragma unroll
        for (int r = 0; r < 8; ++r) {
            int row = row0 + rg * 8 + r;
            if (row < N) {
                U2H o; o.h = (f16x2){(_Float16)(acc[r][0] + b0), (_Float16)(acc[r][1] + b1)};
                *(unsigned*)(xl + (size_t)row * D2 + cc) = o.u;
            }
        }
    } else {
        int cc = 2 * c - 128;
        float b0 = br[cc], b1 = br[cc + 1];
#pragma unroll
        for (int r = 0; r < 8; ++r) {
            int row = row0 + rg * 8 + r;
            if (row < N) {
                U2H o; o.h = (f16x2){(_Float16)(acc[r][0] + b0), (_Float16)(acc[r][1] + b1)};
                *(unsigned*)(xr + (size_t)row * D2 + cc) = o.u;
            }
        }
    }
}

// ---------- CSR build over destination nodes ----------
__global__ void count_k(const int* __restrict__ ei, int E, int Etot, int* __restrict__ counts)
{
    int e = blockIdx.x * 256 + threadIdx.x;
    if (e >= Etot) return;
    int dst = (e < E) ? ei[E + e] : (e - E);
    atomicAdd(&counts[dst], 1);
}

__global__ void scan_k(const int* __restrict__ counts, int* __restrict__ row_ptr,
                       int* __restrict__ offs, int N)
{
    __shared__ int sdata[1024];
    int t = threadIdx.x;
    int chunk = (N + 1023) / 1024;
    int lo = t * chunk, hi = min(lo + chunk, N);
    int p = 0;
    for (int i = lo; i < hi; ++i) p += counts[i];
    sdata[t] = p;
    __syncthreads();
    for (int off = 1; off < 1024; off <<= 1) {
        int v = (t >= off) ? sdata[t - off] : 0;
        __syncthreads();
        sdata[t] += v;
        __syncthreads();
    }
    int run = sdata[t] - p;   // exclusive prefix
    for (int i = lo; i < hi; ++i) { row_ptr[i] = run; offs[i] = run; run += counts[i]; }
    if (t == 1023) row_ptr[N] = sdata[1023];
}

__global__ void scatter_k(const int* __restrict__ ei, int E, int Etot,
                          int* __restrict__ offs, int* __restrict__ csr_src)
{
    int e = blockIdx.x * 256 + threadIdx.x;
    if (e >= Etot) return;
    int src, dst;
    if (e < E) { src = ei[e]; dst = ei[E + e]; } else { src = dst = e - E; }
    int pos = atomicAdd(&offs[dst], 1);
    csr_src[pos] = src;
}

// ---------- layer-1 fused: block = node, wave = head; 16-lane groups × 4 edges ----------
// packed-fp16 scoring (v_pk_add/mul/max + fdot2), fp32 softmax/aggregation.
__global__ __launch_bounds__(256, 8)
void fused1_k(const int* __restrict__ row_ptr, const int* __restrict__ csr_src,
              const __half* __restrict__ xl, const __half* __restrict__ xr,
              const float* __restrict__ att, const float* __restrict__ bias,
              __half* __restrict__ out)
{
    int v = blockIdx.x;
    int t = threadIdx.x;
    int w = t >> 6, lane = t & 63;
    int g = lane >> 4, sub = lane & 15;
    int base = row_ptr[v], deg = row_ptr[v + 1] - base;
    int c0 = (w << 7) + (sub << 3);           // channel in [0,512)

    V16 bb; bb.u4 = *(const uint4*)(xr + (size_t)v * HD1 + c0);
    f16x2 at_h[4];
    {
        float4 t0 = *(const float4*)(att + c0);
        float4 t1 = *(const float4*)(att + c0 + 4);
        at_h[0] = (f16x2){(_Float16)t0.x, (_Float16)t0.y};
        at_h[1] = (f16x2){(_Float16)t0.z, (_Float16)t0.w};
        at_h[2] = (f16x2){(_Float16)t1.x, (_Float16)t1.y};
        at_h[3] = (f16x2){(_Float16)t1.z, (_Float16)t1.w};
    }
    const f16x2 c02 = {(_Float16)0.2f, (_Float16)0.2f};

    float s = 0.f, a[8];
#pragma unroll
    for (int j = 0; j < 8; ++j) a[j] = 0.f;

    for (int i = g; i < deg; i += 4) {
        int src = csr_src[base + i];
        V16 af; af.u4 = *(const uint4*)(xl + (size_t)src * HD1 + c0);
        float p = 0.f;
#pragma unroll
        for (int j = 0; j < 4; ++j) {
            f16x2 th = af.h[j] + bb.h[j];
            f16x2 uh = __builtin_elementwise_max(th, th * c02);
            p = __builtin_amdgcn_fdot2(uh, at_h[j], p, false);
        }
#pragma unroll
        for (int off = 1; off < 16; off <<= 1) p += __shfl_xor(p, off);
        float e = __expf(p);
        s += e;
#pragma unroll
        for (int j = 0; j < 4; ++j) {
            a[2*j]   += e * (float)af.h[j].x;
            a[2*j+1] += e * (float)af.h[j].y;
        }
    }
    s += __shfl_xor(s, 16); s += __shfl_xor(s, 32);
#pragma unroll
    for (int j = 0; j < 8; ++j) { a[j] += __shfl_xor(a[j], 16); a[j] += __shfl_xor(a[j], 32); }

    if (g == 0) {
        float rs = 1.f / s;
        V16 pk;
#pragma unroll
        for (int j = 0; j < 4; ++j)
            pk.h[j] = (f16x2){(_Float16)elu(a[2*j]   * rs + bias[c0 + 2*j]),
                              (_Float16)elu(a[2*j+1] * rs + bias[c0 + 2*j+1])};
        *(uint4*)(out + (size_t)v * HD1 + c0) = pk.u4;
    }
}

// ---------- layer-2 fused: wave = node, 16-lane groups × 4 edges ----------
__global__ __launch_bounds__(256, 8)
void fused2_k(const int* __restrict__ row_ptr, const int* __restrict__ csr_src,
              const __half* __restrict__ xl, const __half* __restrict__ xr,
              const float* __restrict__ att, const float* __restrict__ bias,
              float* __restrict__ out, int N)
{
    int t = threadIdx.x;
    int w = t >> 6, lane = t & 63;
    int v = blockIdx.x * 4 + w;
    if (v >= N) return;
    int g = lane >> 4, sub = lane & 15;
    int base = row_ptr[v], deg = row_ptr[v + 1] - base;
    int c0 = sub << 3;                          // channel in [0,128)

    V16 bb; bb.u4 = *(const uint4*)(xr + (size_t)v * D2 + c0);
    f16x2 at_h[4];
    {
        float4 t0 = *(const float4*)(att + c0);
        float4 t1 = *(const float4*)(att + c0 + 4);
        at_h[0] = (f16x2){(_Float16)t0.x, (_Float16)t0.y};
        at_h[1] = (f16x2){(_Float16)t0.z, (_Float16)t0.w};
        at_h[2] = (f16x2){(_Float16)t1.x, (_Float16)t1.y};
        at_h[3] = (f16x2){(_Float16)t1.z, (_Float16)t1.w};
    }
    const f16x2 c02 = {(_Float16)0.2f, (_Float16)0.2f};

    float s = 0.f, a[8];
#pragma unroll
    for (int j = 0; j < 8; ++j) a[j] = 0.f;

    for (int i = g; i < deg; i += 4) {
        int src = csr_src[base + i];
        V16 af; af.u4 = *(const uint4*)(xl + (size_t)src * D2 + c0);
        float p = 0.f;
#pragma unroll
        for (int j = 0; j < 4; ++j) {
            f16x2 th = af.h[j] + bb.h[j];
            f16x2 uh = __builtin_elementwise_max(th, th * c02);
            p = __builtin_amdgcn_fdot2(uh, at_h[j], p, false);
        }
#pragma unroll
        for (int off = 1; off < 16; off <<= 1) p += __shfl_xor(p, off);
        float e = __expf(p);
        s += e;
#pragma unroll
        for (int j = 0; j < 4; ++j) {
            a[2*j]   += e * (float)af.h[j].x;
            a[2*j+1] += e * (float)af.h[j].y;
        }
    }
    s += __shfl_xor(s, 16); s += __shfl_xor(s, 32);
#pragma unroll
    for (int j = 0; j < 8; ++j) { a[j] += __shfl_xor(a[j], 16); a[j] += __shfl_xor(a[j], 32); }

    if (g == 0) {
        float rs = 1.f / s;
        float o[8];
#pragma unroll
        for (int j = 0; j < 8; ++j) o[j] = elu(a[j] * rs + bias[c0 + j]);
        size_t ob = (size_t)v * D2 + c0;
        *(float4*)(out + ob)     = make_float4(o[0], o[1], o[2], o[3]);
        *(float4*)(out + ob + 4) = make_float4(o[4], o[5], o[6], o[7]);
    }
}

// ---------- mean pool: one block per graph, inline boundary search, no atomics ----------
__global__ void pool2_k(const int* __restrict__ batch, const float* __restrict__ h,
                        float* __restrict__ out, int N)
{
    __shared__ float part[D2];
    int g = blockIdx.x;
    int t = threadIdx.x;
    int c = t & 127, half = t >> 7;
    int lo = 0, hi = N;
    while (lo < hi) { int m = (lo + hi) >> 1; if (batch[m] < g) lo = m + 1; else hi = m; }
    int lo2 = lo, hi2 = N;
    while (lo2 < hi2) { int m = (lo2 + hi2) >> 1; if (batch[m] < g + 1) lo2 = m + 1; else hi2 = m; }
    float acc = 0.f;
    for (int v = lo + half; v < lo2; v += 2)
        acc += h[(size_t)v * D2 + c];
    if (half == 1) part[c] = acc;
    __syncthreads();
    if (half == 0)
        out[(size_t)g * D2 + c] = (acc + part[c]) / fmaxf((float)(lo2 - lo), 1.f);
}

extern "C" void kernel_launch(void* const* d_in, const int* in_sizes, int n_in,
                              void* d_out, int out_size, void* d_ws, size_t ws_size,
                              hipStream_t stream)
{
    const float* x    = (const float*)d_in[0];
    const int*   ei   = (const int*)d_in[1];
    const int*   batch= (const int*)d_in[2];
    const float* Wl1  = (const float*)d_in[3];
    const float* bl1  = (const float*)d_in[4];
    const float* Wr1  = (const float*)d_in[5];
    const float* br1  = (const float*)d_in[6];
    const float* att1 = (const float*)d_in[7];
    const float* bias1= (const float*)d_in[8];
    const float* Wl2  = (const float*)d_in[9];
    const float* bl2  = (const float*)d_in[10];
    const float* Wr2  = (const float*)d_in[11];
    const float* br2  = (const float*)d_in[12];
    const float* att2 = (const float*)d_in[13];
    const float* bias2= (const float*)d_in[14];
    float* out = (float*)d_out;

    int N    = in_sizes[2];          // batch vector length = nodes
    int E    = in_sizes[1] / 2;      // directed edges (before self-loops)
    int Etot = E + N;
    int G    = out_size / D2;

    char* ws = (char*)d_ws;
    size_t off = 0;
    auto alloc = [&](size_t bytes) -> void* {
        void* p = ws + off;
        off = (off + bytes + 255) & ~(size_t)255;
        return p;
    };
    __half*   xl1h   = (__half*)alloc((size_t)N * HD1 * 2);
    __half*   xr1h   = (__half*)alloc((size_t)N * HD1 * 2);
    __half*   h1h    = (__half*)alloc((size_t)N * HD1 * 2);
    __half*   xl2h   = (__half*)alloc((size_t)N * D2 * 2);
    __half*   xr2h   = (__half*)alloc((size_t)N * D2 * 2);
    float*    h2     = (float*)alloc((size_t)N * D2 * 4);
    unsigned* Wt1    = (unsigned*)alloc((size_t)1024 * KP1 * 4);
    unsigned* Wt2    = (unsigned*)alloc((size_t)256 * 256 * 4);
    int*      counts = (int*)alloc((size_t)(N + 1) * 4);
    int*      offs   = (int*)alloc((size_t)(N + 1) * 4);
    int*      row_ptr= (int*)alloc((size_t)(N + 1) * 4);
    int*      csr_src= (int*)alloc((size_t)Etot * 4);

    int wtot = 1024 * KP1 + 256 * 256;
    (void)hipMemsetAsync(counts, 0, (size_t)(N + 1) * 4, stream);
    cvtW_k<<<(wtot + 255) / 256, 256, 0, stream>>>(Wl1, Wr1, Wl2, Wr2, Wt1, Wt2);
    gemm1_k<<<(N + 15) / 16, 256, 0, stream>>>(x, Wt1, bl1, br1, xl1h, xr1h, N);
    count_k<<<(Etot + 255) / 256, 256, 0, stream>>>(ei, E, Etot, counts);
    scan_k<<<1, 1024, 0, stream>>>(counts, row_ptr, offs, N);
    scatter_k<<<(Etot + 255) / 256, 256, 0, stream>>>(ei, E, Etot, offs, csr_src);
    fused1_k<<<N, 256, 0, stream>>>(row_ptr, csr_src, xl1h, xr1h, att1, bias1, h1h);
    gemm2_k<<<(N + 15) / 16, 256, 0, stream>>>(h1h, Wt2, bl2, br2, xl2h, xr2h, N);
    fused2_k<<<(N + 3) / 4, 256, 0, stream>>>(row_ptr, csr_src, xl2h, xr2h, att2, bias2, h2, N);
    pool2_k<<<G, 256, 0, stream>>>(batch, h2, out, N);
}

// Round 14
// 242.431 us; speedup vs baseline: 1.3770x; 1.3770x over previous
//
#include <hip/hip_runtime.h>
#include <hip/hip_fp16.h>
#include <math.h>

#define FIN 78
#define HD1 512
#define D2  128
#define KP1 40   // layer-1 k-pairs (78 padded to 80)

typedef _Float16 f16x2 __attribute__((ext_vector_type(2)));
union U2H { unsigned u; f16x2 h; __half2 hh; };
__device__ __forceinline__ f16x2 u2h(unsigned u) { U2H x; x.u = u; return x.h; }
union V16 { uint4 u4; f16x2 h[4]; };

__device__ __forceinline__ float elu(float x) { return x > 0.f ? x : expf(x) - 1.f; }

// ---------- W pack (k-major): Wt1[k2][1024] ; Wt2[k2][256] ----------
__global__ void cvtW_k(const float* __restrict__ Wl1, const float* __restrict__ Wr1,
                       const float* __restrict__ Wl2, const float* __restrict__ Wr2,
                       unsigned* __restrict__ Wt1, unsigned* __restrict__ Wt2)
{
    int idx = blockIdx.x * 256 + threadIdx.x;
    if (idx < 1024 * KP1) {
        int k2 = idx >> 10, col = idx & 1023;          // Wt1[k2*1024 + col]
        const float* W = (col < HD1) ? Wl1 : Wr1;
        int c = (col < HD1) ? col : col - HD1;
        float w0 = (2 * k2     < FIN) ? W[(2 * k2)     * HD1 + c] : 0.f;
        float w1 = (2 * k2 + 1 < FIN) ? W[(2 * k2 + 1) * HD1 + c] : 0.f;
        U2H x; x.h = (f16x2){(_Float16)w0, (_Float16)w1};
        Wt1[idx] = x.u;
    } else if (idx < 1024 * KP1 + 256 * 256) {
        int j = idx - 1024 * KP1;
        int k2 = j >> 8, col = j & 255;                // Wt2[k2*256 + col]
        const float* W = (col < D2) ? Wl2 : Wr2;
        int c = (col < D2) ? col : col - D2;
        float w0 = W[(2 * k2) * D2 + c], w1 = W[(2 * k2 + 1) * D2 + c];
        U2H x; x.h = (f16x2){(_Float16)w0, (_Float16)w1};
        Wt2[j] = x.u;
    }
}

// ---------- layer-1 GEMM via fdot2: x[N,78] @ Wt1 -> xl,xr fp16 ----------
// block: 16 rows x 1024 cols; thread: 16 rows x 4 cols; coalesced W reads.
__global__ __launch_bounds__(256, 4)
void gemm1_k(const float* __restrict__ x, const unsigned* __restrict__ Wt1,
             const float* __restrict__ bl, const float* __restrict__ br,
             __half* __restrict__ xl, __half* __restrict__ xr, int N)
{
    __shared__ unsigned hs[16][KP1];
    int row0 = blockIdx.x * 16;
    int t = threadIdx.x;
    for (int idx = t; idx < 16 * KP1; idx += 256) {
        int r = idx / KP1, k2 = idx - r * KP1;
        int row = row0 + r;
        float lo = 0.f, hi = 0.f;
        if (row < N) {
            lo = (2 * k2     < FIN) ? x[(size_t)row * FIN + 2 * k2]     : 0.f;
            hi = (2 * k2 + 1 < FIN) ? x[(size_t)row * FIN + 2 * k2 + 1] : 0.f;
        }
        U2H p; p.h = (f16x2){(_Float16)lo, (_Float16)hi};
        hs[r][k2] = p.u;
    }
    __syncthreads();

    float acc[16][4];
#pragma unroll
    for (int r = 0; r < 16; ++r)
        { acc[r][0]=0.f; acc[r][1]=0.f; acc[r][2]=0.f; acc[r][3]=0.f; }

    for (int k2 = 0; k2 < KP1; ++k2) {
        const unsigned* wp = Wt1 + (size_t)k2 * 1024;
        unsigned w0 = wp[t], w1 = wp[t + 256], w2 = wp[t + 512], w3 = wp[t + 768];
#pragma unroll
        for (int r = 0; r < 16; ++r) {
            f16x2 xv = u2h(hs[r][k2]);
            acc[r][0] = __builtin_amdgcn_fdot2(xv, u2h(w0), acc[r][0], false);
            acc[r][1] = __builtin_amdgcn_fdot2(xv, u2h(w1), acc[r][1], false);
            acc[r][2] = __builtin_amdgcn_fdot2(xv, u2h(w2), acc[r][2], false);
            acc[r][3] = __builtin_amdgcn_fdot2(xv, u2h(w3), acc[r][3], false);
        }
    }

#pragma unroll
    for (int i = 0; i < 4; ++i) {
        int j = t + i * 256;
        bool isL = j < HD1;
        int col = isL ? j : j - HD1;
        float b = isL ? bl[col] : br[col];
        __half* outp = isL ? xl : xr;
        for (int r = 0; r < 16; ++r) {
            int row = row0 + r;
            if (row < N) outp[(size_t)row * HD1 + col] = __float2half(acc[r][i] + b);
        }
    }
}

// ---------- layer-2 GEMM via fdot2: h1[N,512]f16 @ Wt2 -> xl2,xr2 fp16 ----------
__global__ __launch_bounds__(256, 4)
void gemm2_k(const __half* __restrict__ h, const unsigned* __restrict__ Wt,
             const float* __restrict__ bl, const float* __restrict__ br,
             __half* __restrict__ xl, __half* __restrict__ xr, int N)
{
    __shared__ unsigned hs[16][256];
    int row0 = blockIdx.x * 16;
    int t = threadIdx.x;
    for (int idx = t; idx < 16 * 64; idx += 256) {
        int r = idx >> 6, q = idx & 63;
        int row = row0 + r;
        uint4 val = make_uint4(0u, 0u, 0u, 0u);
        if (row < N) val = *(const uint4*)(h + (size_t)row * HD1 + q * 8);
        *(uint4*)&hs[r][q * 4] = val;
    }
    __syncthreads();

    int c = t & 127, rg = t >> 7;                // cols 2c,2c+1; rows rg*8..rg*8+7
    float acc[8][2];
#pragma unroll
    for (int r = 0; r < 8; ++r) { acc[r][0] = 0.f; acc[r][1] = 0.f; }

    for (int k2 = 0; k2 < 256; ++k2) {
        uint2 w01 = *(const uint2*)(Wt + (size_t)k2 * 256 + 2 * c);   // coalesced
        f16x2 w0 = u2h(w01.x), w1 = u2h(w01.y);
#pragma unroll
        for (int r = 0; r < 8; ++r) {
            f16x2 hv = u2h(hs[rg * 8 + r][k2]);
            acc[r][0] = __builtin_amdgcn_fdot2(hv, w0, acc[r][0], false);
            acc[r][1] = __builtin_amdgcn_fdot2(hv, w1, acc[r][1], false);
        }
    }

    if (c < 64) {
        int cc = 2 * c;
        float b0 = bl[cc], b1 = bl[cc + 1];
#pragma unroll
        for (int r = 0; r < 8; ++r) {
            int row = row0 + rg * 8 + r;
            if (row < N) {
                U2H o; o.h = (f16x2){(_Float16)(acc[r][0] + b0), (_Float16)(acc[r][1] + b1)};
                *(unsigned*)(xl + (size_t)row * D2 + cc) = o.u;
            }
        }
    } else {
        int cc = 2 * c - 128;
        float b0 = br[cc], b1 = br[cc + 1];
#pragma unroll
        for (int r = 0; r < 8; ++r) {
            int row = row0 + rg * 8 + r;
            if (row < N) {
                U2H o; o.h = (f16x2){(_Float16)(acc[r][0] + b0), (_Float16)(acc[r][1] + b1)};
                *(unsigned*)(xr + (size_t)row * D2 + cc) = o.u;
            }
        }
    }
}

// ---------- CSR build over destination nodes ----------
__global__ void count_k(const int* __restrict__ ei, int E, int Etot, int* __restrict__ counts)
{
    int e = blockIdx.x * 256 + threadIdx.x;
    if (e >= Etot) return;
    int dst = (e < E) ? ei[E + e] : (e - E);
    atomicAdd(&counts[dst], 1);
}

__global__ void scan_k(const int* __restrict__ counts, int* __restrict__ row_ptr,
                       int* __restrict__ offs, int N)
{
    __shared__ int sdata[1024];
    int t = threadIdx.x;
    int chunk = (N + 1023) / 1024;
    int lo = t * chunk, hi = min(lo + chunk, N);
    int p = 0;
    for (int i = lo; i < hi; ++i) p += counts[i];
    sdata[t] = p;
    __syncthreads();
    for (int off = 1; off < 1024; off <<= 1) {
        int v = (t >= off) ? sdata[t - off] : 0;
        __syncthreads();
        sdata[t] += v;
        __syncthreads();
    }
    int run = sdata[t] - p;   // exclusive prefix
    for (int i = lo; i < hi; ++i) { row_ptr[i] = run; offs[i] = run; run += counts[i]; }
    if (t == 1023) row_ptr[N] = sdata[1023];
}

__global__ void scatter_k(const int* __restrict__ ei, int E, int Etot,
                          int* __restrict__ offs, int* __restrict__ csr_src)
{
    int e = blockIdx.x * 256 + threadIdx.x;
    if (e >= Etot) return;
    int src, dst;
    if (e < E) { src = ei[e]; dst = ei[E + e]; } else { src = dst = e - E; }
    int pos = atomicAdd(&offs[dst], 1);
    csr_src[pos] = src;
}

// ---------- layer-1 fused: block = node, wave = head; 16-lane groups × 4 edges ----------
// packed-fp16 scoring (v_pk_add/mul/max + fdot2), fp32 softmax/aggregation.
__global__ __launch_bounds__(256, 8)
void fused1_k(const int* __restrict__ row_ptr, const int* __restrict__ csr_src,
              const __half* __restrict__ xl, const __half* __restrict__ xr,
              const float* __restrict__ att, const float* __restrict__ bias,
              __half* __restrict__ out)
{
    int v = blockIdx.x;
    int t = threadIdx.x;
    int w = t >> 6, lane = t & 63;
    int g = lane >> 4, sub = lane & 15;
    int base = row_ptr[v], deg = row_ptr[v + 1] - base;
    int c0 = (w << 7) + (sub << 3);           // channel in [0,512)

    V16 bb; bb.u4 = *(const uint4*)(xr + (size_t)v * HD1 + c0);
    f16x2 at_h[4];
    {
        float4 t0 = *(const float4*)(att + c0);
        float4 t1 = *(const float4*)(att + c0 + 4);
        at_h[0] = (f16x2){(_Float16)t0.x, (_Float16)t0.y};
        at_h[1] = (f16x2){(_Float16)t0.z, (_Float16)t0.w};
        at_h[2] = (f16x2){(_Float16)t1.x, (_Float16)t1.y};
        at_h[3] = (f16x2){(_Float16)t1.z, (_Float16)t1.w};
    }
    const f16x2 c02 = {(_Float16)0.2f, (_Float16)0.2f};

    float s = 0.f, a[8];
#pragma unroll
    for (int j = 0; j < 8; ++j) a[j] = 0.f;

    for (int i = g; i < deg; i += 4) {
        int src = csr_src[base + i];
        V16 af; af.u4 = *(const uint4*)(xl + (size_t)src * HD1 + c0);
        float p = 0.f;
#pragma unroll
        for (int j = 0; j < 4; ++j) {
            f16x2 th = af.h[j] + bb.h[j];
            f16x2 uh = __builtin_elementwise_max(th, th * c02);
            p = __builtin_amdgcn_fdot2(uh, at_h[j], p, false);
        }
#pragma unroll
        for (int off = 1; off < 16; off <<= 1) p += __shfl_xor(p, off);
        float e = __expf(p);
        s += e;
#pragma unroll
        for (int j = 0; j < 4; ++j) {
            a[2*j]   += e * (float)af.h[j].x;
            a[2*j+1] += e * (float)af.h[j].y;
        }
    }
    s += __shfl_xor(s, 16); s += __shfl_xor(s, 32);
#pragma unroll
    for (int j = 0; j < 8; ++j) { a[j] += __shfl_xor(a[j], 16); a[j] += __shfl_xor(a[j], 32); }

    if (g == 0) {
        float rs = 1.f / s;
        V16 pk;
#pragma unroll
        for (int j = 0; j < 4; ++j)
            pk.h[j] = (f16x2){(_Float16)elu(a[2*j]   * rs + bias[c0 + 2*j]),
                              (_Float16)elu(a[2*j+1] * rs + bias[c0 + 2*j+1])};
        *(uint4*)(out + (size_t)v * HD1 + c0) = pk.u4;
    }
}

// ---------- layer-2 fused: wave = node, 16-lane groups × 4 edges ----------
__global__ __launch_bounds__(256, 8)
void fused2_k(const int* __restrict__ row_ptr, const int* __restrict__ csr_src,
              const __half* __restrict__ xl, const __half* __restrict__ xr,
              const float* __restrict__ att, const float* __restrict__ bias,
              float* __restrict__ out, int N)
{
    int t = threadIdx.x;
    int w = t >> 6, lane = t & 63;
    int v = blockIdx.x * 4 + w;
    if (v >= N) return;
    int g = lane >> 4, sub = lane & 15;
    int base = row_ptr[v], deg = row_ptr[v + 1] - base;
    int c0 = sub << 3;                          // channel in [0,128)

    V16 bb; bb.u4 = *(const uint4*)(xr + (size_t)v * D2 + c0);
    f16x2 at_h[4];
    {
        float4 t0 = *(const float4*)(att + c0);
        float4 t1 = *(const float4*)(att + c0 + 4);
        at_h[0] = (f16x2){(_Float16)t0.x, (_Float16)t0.y};
        at_h[1] = (f16x2){(_Float16)t0.z, (_Float16)t0.w};
        at_h[2] = (f16x2){(_Float16)t1.x, (_Float16)t1.y};
        at_h[3] = (f16x2){(_Float16)t1.z, (_Float16)t1.w};
    }
    const f16x2 c02 = {(_Float16)0.2f, (_Float16)0.2f};

    float s = 0.f, a[8];
#pragma unroll
    for (int j = 0; j < 8; ++j) a[j] = 0.f;

    for (int i = g; i < deg; i += 4) {
        int src = csr_src[base + i];
        V16 af; af.u4 = *(const uint4*)(xl + (size_t)src * D2 + c0);
        float p = 0.f;
#pragma unroll
        for (int j = 0; j < 4; ++j) {
            f16x2 th = af.h[j] + bb.h[j];
            f16x2 uh = __builtin_elementwise_max(th, th * c02);
            p = __builtin_amdgcn_fdot2(uh, at_h[j], p, false);
        }
#pragma unroll
        for (int off = 1; off < 16; off <<= 1) p += __shfl_xor(p, off);
        float e = __expf(p);
        s += e;
#pragma unroll
        for (int j = 0; j < 4; ++j) {
            a[2*j]   += e * (float)af.h[j].x;
            a[2*j+1] += e * (float)af.h[j].y;
        }
    }
    s += __shfl_xor(s, 16); s += __shfl_xor(s, 32);
#pragma unroll
    for (int j = 0; j < 8; ++j) { a[j] += __shfl_xor(a[j], 16); a[j] += __shfl_xor(a[j], 32); }

    if (g == 0) {
        float rs = 1.f / s;
        float o[8];
#pragma unroll
        for (int j = 0; j < 8; ++j) o[j] = elu(a[j] * rs + bias[c0 + j]);
        size_t ob = (size_t)v * D2 + c0;
        *(float4*)(out + ob)     = make_float4(o[0], o[1], o[2], o[3]);
        *(float4*)(out + ob + 4) = make_float4(o[4], o[5], o[6], o[7]);
    }
}

// ---------- mean pool: one block per graph, inline boundary search, no atomics ----------
__global__ void pool2_k(const int* __restrict__ batch, const float* __restrict__ h,
                        float* __restrict__ out, int N)
{
    __shared__ float part[D2];
    int g = blockIdx.x;
    int t = threadIdx.x;
    int c = t & 127, half = t >> 7;
    int lo = 0, hi = N;
    while (lo < hi) { int m = (lo + hi) >> 1; if (batch[m] < g) lo = m + 1; else hi = m; }
    int lo2 = lo, hi2 = N;
    while (lo2 < hi2) { int m = (lo2 + hi2) >> 1; if (batch[m] < g + 1) lo2 = m + 1; else hi2 = m; }
    float acc = 0.f;
    for (int v = lo + half; v < lo2; v += 2)
        acc += h[(size_t)v * D2 + c];
    if (half == 1) part[c] = acc;
    __syncthreads();
    if (half == 0)
        out[(size_t)g * D2 + c] = (acc + part[c]) / fmaxf((float)(lo2 - lo), 1.f);
}

extern "C" void kernel_launch(void* const* d_in, const int* in_sizes, int n_in,
                              void* d_out, int out_size, void* d_ws, size_t ws_size,
                              hipStream_t stream)
{
    const float* x    = (const float*)d_in[0];
    const int*   ei   = (const int*)d_in[1];
    const int*   batch= (const int*)d_in[2];
    const float* Wl1  = (const float*)d_in[3];
    const float* bl1  = (const float*)d_in[4];
    const float* Wr1  = (const float*)d_in[5];
    const float* br1  = (const float*)d_in[6];
    const float* att1 = (const float*)d_in[7];
    const float* bias1= (const float*)d_in[8];
    const float* Wl2  = (const float*)d_in[9];
    const float* bl2  = (const float*)d_in[10];
    const float* Wr2  = (const float*)d_in[11];
    const float* br2  = (const float*)d_in[12];
    const float* att2 = (const float*)d_in[13];
    const float* bias2= (const float*)d_in[14];
    float* out = (float*)d_out;

    int N    = in_sizes[2];          // batch vector length = nodes
    int E    = in_sizes[1] / 2;      // directed edges (before self-loops)
    int Etot = E + N;
    int G    = out_size / D2;

    char* ws = (char*)d_ws;
    size_t off = 0;
    auto alloc = [&](size_t bytes) -> void* {
        void* p = ws + off;
        off = (off + bytes + 255) & ~(size_t)255;
        return p;
    };
    __half*   xl1h   = (__half*)alloc((size_t)N * HD1 * 2);
    __half*   xr1h   = (__half*)alloc((size_t)N * HD1 * 2);
    __half*   h1h    = (__half*)alloc((size_t)N * HD1 * 2);
    __half*   xl2h   = (__half*)alloc((size_t)N * D2 * 2);
    __half*   xr2h   = (__half*)alloc((size_t)N * D2 * 2);
    float*    h2     = (float*)alloc((size_t)N * D2 * 4);
    unsigned* Wt1    = (unsigned*)alloc((size_t)1024 * KP1 * 4);
    unsigned* Wt2    = (unsigned*)alloc((size_t)256 * 256 * 4);
    int*      counts = (int*)alloc((size_t)(N + 1) * 4);
    int*      offs   = (int*)alloc((size_t)(N + 1) * 4);
    int*      row_ptr= (int*)alloc((size_t)(N + 1) * 4);
    int*      csr_src= (int*)alloc((size_t)Etot * 4);

    int wtot = 1024 * KP1 + 256 * 256;
    (void)hipMemsetAsync(counts, 0, (size_t)(N + 1) * 4, stream);
    cvtW_k<<<(wtot + 255) / 256, 256, 0, stream>>>(Wl1, Wr1, Wl2, Wr2, Wt1, Wt2);
    gemm1_k<<<(N + 15) / 16, 256, 0, stream>>>(x, Wt1, bl1, br1, xl1h, xr1h, N);
    count_k<<<(Etot + 255) / 256, 256, 0, stream>>>(ei, E, Etot, counts);
    scan_k<<<1, 1024, 0, stream>>>(counts, row_ptr, offs, N);
    scatter_k<<<(Etot + 255) / 256, 256, 0, stream>>>(ei, E, Etot, offs, csr_src);
    fused1_k<<<N, 256, 0, stream>>>(row_ptr, csr_src, xl1h, xr1h, att1, bias1, h1h);
    gemm2_k<<<(N + 15) / 16, 256, 0, stream>>>(h1h, Wt2, bl2, br2, xl2h, xr2h, N);
    fused2_k<<<(N + 3) / 4, 256, 0, stream>>>(row_ptr, csr_src, xl2h, xr2h, att2, bias2, h2, N);
    pool2_k<<<G, 256, 0, stream>>>(batch, h2, out, N);
}

// Round 16
// 234.106 us; speedup vs baseline: 1.4259x; 1.0356x over previous
//
#include <hip/hip_runtime.h>
#include <hip/hip_fp16.h>
#include <math.h>

#define FIN 78
#define HD1 512
#define D2  128
#define KP1 40   // layer-1 k-pairs (78 padded to 80)

typedef _Float16 f16x2 __attribute__((ext_vector_type(2)));
union U2H { unsigned u; f16x2 h; __half2 hh; };
__device__ __forceinline__ f16x2 u2h(unsigned u) { U2H x; x.u = u; return x.h; }
union V16 { uint4 u4; f16x2 h[4]; };

__device__ __forceinline__ float elu(float x) { return x > 0.f ? x : expf(x) - 1.f; }

// ---------- prep: W pack (k-major) + edge count, grid-partitioned ----------
__global__ void prep_k(const float* __restrict__ Wl1, const float* __restrict__ Wr1,
                       const float* __restrict__ Wl2, const float* __restrict__ Wr2,
                       unsigned* __restrict__ Wt1, unsigned* __restrict__ Wt2,
                       const int* __restrict__ ei, int E, int Etot,
                       int* __restrict__ counts, int nWB)
{
    if ((int)blockIdx.x < nWB) {
        int idx = blockIdx.x * 256 + threadIdx.x;
        if (idx < 1024 * KP1) {
            int k2 = idx >> 10, col = idx & 1023;          // Wt1[k2*1024 + col]
            const float* W = (col < HD1) ? Wl1 : Wr1;
            int c = (col < HD1) ? col : col - HD1;
            float w0 = (2 * k2     < FIN) ? W[(2 * k2)     * HD1 + c] : 0.f;
            float w1 = (2 * k2 + 1 < FIN) ? W[(2 * k2 + 1) * HD1 + c] : 0.f;
            U2H x; x.h = (f16x2){(_Float16)w0, (_Float16)w1};
            Wt1[idx] = x.u;
        } else if (idx < 1024 * KP1 + 256 * 256) {
            int j = idx - 1024 * KP1;
            int k2 = j >> 8, col = j & 255;                // Wt2[k2*256 + col]
            const float* W = (col < D2) ? Wl2 : Wr2;
            int c = (col < D2) ? col : col - D2;
            float w0 = W[(2 * k2) * D2 + c], w1 = W[(2 * k2 + 1) * D2 + c];
            U2H x; x.h = (f16x2){(_Float16)w0, (_Float16)w1};
            Wt2[j] = x.u;
        }
    } else {
        int e = (blockIdx.x - nWB) * 256 + threadIdx.x;
        if (e >= Etot) return;
        int dst = (e < E) ? ei[E + e] : (e - E);
        atomicAdd(&counts[dst], 1);
    }
}

// ---------- layer-1 GEMM via fdot2: x[N,78] @ Wt1 -> xl,xr fp16 ----------
__global__ __launch_bounds__(256, 4)
void gemm1_k(const float* __restrict__ x, const unsigned* __restrict__ Wt1,
             const float* __restrict__ bl, const float* __restrict__ br,
             __half* __restrict__ xl, __half* __restrict__ xr, int N)
{
    __shared__ unsigned hs[16][KP1];
    int row0 = blockIdx.x * 16;
    int t = threadIdx.x;
    for (int idx = t; idx < 16 * KP1; idx += 256) {
        int r = idx / KP1, k2 = idx - r * KP1;
        int row = row0 + r;
        float lo = 0.f, hi = 0.f;
        if (row < N) {
            lo = (2 * k2     < FIN) ? x[(size_t)row * FIN + 2 * k2]     : 0.f;
            hi = (2 * k2 + 1 < FIN) ? x[(size_t)row * FIN + 2 * k2 + 1] : 0.f;
        }
        U2H p; p.h = (f16x2){(_Float16)lo, (_Float16)hi};
        hs[r][k2] = p.u;
    }
    __syncthreads();

    float acc[16][4];
#pragma unroll
    for (int r = 0; r < 16; ++r)
        { acc[r][0]=0.f; acc[r][1]=0.f; acc[r][2]=0.f; acc[r][3]=0.f; }

    for (int k2 = 0; k2 < KP1; ++k2) {
        const unsigned* wp = Wt1 + (size_t)k2 * 1024;
        unsigned w0 = wp[t], w1 = wp[t + 256], w2 = wp[t + 512], w3 = wp[t + 768];
#pragma unroll
        for (int r = 0; r < 16; ++r) {
            f16x2 xv = u2h(hs[r][k2]);
            acc[r][0] = __builtin_amdgcn_fdot2(xv, u2h(w0), acc[r][0], false);
            acc[r][1] = __builtin_amdgcn_fdot2(xv, u2h(w1), acc[r][1], false);
            acc[r][2] = __builtin_amdgcn_fdot2(xv, u2h(w2), acc[r][2], false);
            acc[r][3] = __builtin_amdgcn_fdot2(xv, u2h(w3), acc[r][3], false);
        }
    }

#pragma unroll
    for (int i = 0; i < 4; ++i) {
        int j = t + i * 256;
        bool isL = j < HD1;
        int col = isL ? j : j - HD1;
        float b = isL ? bl[col] : br[col];
        __half* outp = isL ? xl : xr;
        for (int r = 0; r < 16; ++r) {
            int row = row0 + r;
            if (row < N) outp[(size_t)row * HD1 + col] = __float2half(acc[r][i] + b);
        }
    }
}

// ---------- layer-2 GEMM via fdot2: h1[N,512]f16 @ Wt2 -> xl2,xr2 fp16 ----------
__global__ __launch_bounds__(256, 4)
void gemm2_k(const __half* __restrict__ h, const unsigned* __restrict__ Wt,
             const float* __restrict__ bl, const float* __restrict__ br,
             __half* __restrict__ xl, __half* __restrict__ xr, int N)
{
    __shared__ unsigned hs[16][256];
    int row0 = blockIdx.x * 16;
    int t = threadIdx.x;
    for (int idx = t; idx < 16 * 64; idx += 256) {
        int r = idx >> 6, q = idx & 63;
        int row = row0 + r;
        uint4 val = make_uint4(0u, 0u, 0u, 0u);
        if (row < N) val = *(const uint4*)(h + (size_t)row * HD1 + q * 8);
        *(uint4*)&hs[r][q * 4] = val;
    }
    __syncthreads();

    int c = t & 127, rg = t >> 7;                // cols 2c,2c+1; rows rg*8..rg*8+7
    float acc[8][2];
#pragma unroll
    for (int r = 0; r < 8; ++r) { acc[r][0] = 0.f; acc[r][1] = 0.f; }

    for (int k2 = 0; k2 < 256; ++k2) {
        uint2 w01 = *(const uint2*)(Wt + (size_t)k2 * 256 + 2 * c);   // coalesced
        f16x2 w0 = u2h(w01.x), w1 = u2h(w01.y);
#pragma unroll
        for (int r = 0; r < 8; ++r) {
            f16x2 hv = u2h(hs[rg * 8 + r][k2]);
            acc[r][0] = __builtin_amdgcn_fdot2(hv, w0, acc[r][0], false);
            acc[r][1] = __builtin_amdgcn_fdot2(hv, w1, acc[r][1], false);
        }
    }

    if (c < 64) {
        int cc = 2 * c;
        float b0 = bl[cc], b1 = bl[cc + 1];
#pragma unroll
        for (int r = 0; r < 8; ++r) {
            int row = row0 + rg * 8 + r;
            if (row < N) {
                U2H o; o.h = (f16x2){(_Float16)(acc[r][0] + b0), (_Float16)(acc[r][1] + b1)};
                *(unsigned*)(xl + (size_t)row * D2 + cc) = o.u;
            }
        }
    } else {
        int cc = 2 * c - 128;
        float b0 = br[cc], b1 = br[cc + 1];
#pragma unroll
        for (int r = 0; r < 8; ++r) {
            int row = row0 + rg * 8 + r;
            if (row < N) {
                U2H o; o.h = (f16x2){(_Float16)(acc[r][0] + b0), (_Float16)(acc[r][1] + b1)};
                *(unsigned*)(xr + (size_t)row * D2 + cc) = o.u;
            }
        }
    }
}

// ---------- CSR scan + scatter ----------
__global__ void scan_k(const int* __restrict__ counts, int* __restrict__ row_ptr,
                       int* __restrict__ offs, int N)
{
    __shared__ int sdata[1024];
    int t = threadIdx.x;
    int chunk = (N + 1023) / 1024;
    int lo = t * chunk, hi = min(lo + chunk, N);
    int p = 0;
    for (int i = lo; i < hi; ++i) p += counts[i];
    sdata[t] = p;
    __syncthreads();
    for (int off = 1; off < 1024; off <<= 1) {
        int v = (t >= off) ? sdata[t - off] : 0;
        __syncthreads();
        sdata[t] += v;
        __syncthreads();
    }
    int run = sdata[t] - p;   // exclusive prefix
    for (int i = lo; i < hi; ++i) { row_ptr[i] = run; offs[i] = run; run += counts[i]; }
    if (t == 1023) row_ptr[N] = sdata[1023];
}

__global__ void scatter_k(const int* __restrict__ ei, int E, int Etot,
                          int* __restrict__ offs, int* __restrict__ csr_src)
{
    int e = blockIdx.x * 256 + threadIdx.x;
    if (e >= Etot) return;
    int src, dst;
    if (e < E) { src = ei[e]; dst = ei[E + e]; } else { src = dst = e - E; }
    int pos = atomicAdd(&offs[dst], 1);
    csr_src[pos] = src;
}

// ---------- layer-1 fused: block = node, wave = head; 16-lane groups × 4 edges ----------
// packed-fp16 scoring, fp32 softmax/agg, 1-deep software prefetch of next edge row.
__global__ __launch_bounds__(256, 8)
void fused1_k(const int* __restrict__ row_ptr, const int* __restrict__ csr_src,
              const __half* __restrict__ xl, const __half* __restrict__ xr,
              const float* __restrict__ att, const float* __restrict__ bias,
              __half* __restrict__ out)
{
    int v = blockIdx.x;
    int t = threadIdx.x;
    int w = t >> 6, lane = t & 63;
    int g = lane >> 4, sub = lane & 15;
    int base = row_ptr[v], deg = row_ptr[v + 1] - base;
    int c0 = (w << 7) + (sub << 3);           // channel in [0,512)

    V16 bb; bb.u4 = *(const uint4*)(xr + (size_t)v * HD1 + c0);
    f16x2 at_h[4];
    {
        float4 t0 = *(const float4*)(att + c0);
        float4 t1 = *(const float4*)(att + c0 + 4);
        at_h[0] = (f16x2){(_Float16)t0.x, (_Float16)t0.y};
        at_h[1] = (f16x2){(_Float16)t0.z, (_Float16)t0.w};
        at_h[2] = (f16x2){(_Float16)t1.x, (_Float16)t1.y};
        at_h[3] = (f16x2){(_Float16)t1.z, (_Float16)t1.w};
    }
    const f16x2 c02 = {(_Float16)0.2f, (_Float16)0.2f};

    float s = 0.f, a[8];
#pragma unroll
    for (int j = 0; j < 8; ++j) a[j] = 0.f;

    V16 afn;
    if (g < deg)
        afn.u4 = *(const uint4*)(xl + (size_t)csr_src[base + g] * HD1 + c0);

    for (int i = g; i < deg; i += 4) {
        V16 af = afn;
        int inext = i + 4;
        if (inext < deg)
            afn.u4 = *(const uint4*)(xl + (size_t)csr_src[base + inext] * HD1 + c0);
        float p = 0.f;
#pragma unroll
        for (int j = 0; j < 4; ++j) {
            f16x2 th = af.h[j] + bb.h[j];
            f16x2 uh = __builtin_elementwise_max(th, th * c02);
            p = __builtin_amdgcn_fdot2(uh, at_h[j], p, false);
        }
#pragma unroll
        for (int off = 1; off < 16; off <<= 1) p += __shfl_xor(p, off);
        float e = __expf(p);
        s += e;
#pragma unroll
        for (int j = 0; j < 4; ++j) {
            a[2*j]   += e * (float)af.h[j].x;
            a[2*j+1] += e * (float)af.h[j].y;
        }
    }
    s += __shfl_xor(s, 16); s += __shfl_xor(s, 32);
#pragma unroll
    for (int j = 0; j < 8; ++j) { a[j] += __shfl_xor(a[j], 16); a[j] += __shfl_xor(a[j], 32); }

    if (g == 0) {
        float rs = 1.f / s;
        V16 pk;
#pragma unroll
        for (int j = 0; j < 4; ++j)
            pk.h[j] = (f16x2){(_Float16)elu(a[2*j]   * rs + bias[c0 + 2*j]),
                              (_Float16)elu(a[2*j+1] * rs + bias[c0 + 2*j+1])};
        *(uint4*)(out + (size_t)v * HD1 + c0) = pk.u4;
    }
}

// ---------- layer-2 fused: wave = node, 16-lane groups × 4 edges; prefetched ----------
__global__ __launch_bounds__(256, 8)
void fused2_k(const int* __restrict__ row_ptr, const int* __restrict__ csr_src,
              const __half* __restrict__ xl, const __half* __restrict__ xr,
              const float* __restrict__ att, const float* __restrict__ bias,
              float* __restrict__ out, int N)
{
    int t = threadIdx.x;
    int w = t >> 6, lane = t & 63;
    int v = blockIdx.x * 4 + w;
    if (v >= N) return;
    int g = lane >> 4, sub = lane & 15;
    int base = row_ptr[v], deg = row_ptr[v + 1] - base;
    int c0 = sub << 3;                          // channel in [0,128)

    V16 bb; bb.u4 = *(const uint4*)(xr + (size_t)v * D2 + c0);
    f16x2 at_h[4];
    {
        float4 t0 = *(const float4*)(att + c0);
        float4 t1 = *(const float4*)(att + c0 + 4);
        at_h[0] = (f16x2){(_Float16)t0.x, (_Float16)t0.y};
        at_h[1] = (f16x2){(_Float16)t0.z, (_Float16)t0.w};
        at_h[2] = (f16x2){(_Float16)t1.x, (_Float16)t1.y};
        at_h[3] = (f16x2){(_Float16)t1.z, (_Float16)t1.w};
    }
    const f16x2 c02 = {(_Float16)0.2f, (_Float16)0.2f};

    float s = 0.f, a[8];
#pragma unroll
    for (int j = 0; j < 8; ++j) a[j] = 0.f;

    V16 afn;
    if (g < deg)
        afn.u4 = *(const uint4*)(xl + (size_t)csr_src[base + g] * D2 + c0);

    for (int i = g; i < deg; i += 4) {
        V16 af = afn;
        int inext = i + 4;
        if (inext < deg)
            afn.u4 = *(const uint4*)(xl + (size_t)csr_src[base + inext] * D2 + c0);
        float p = 0.f;
#pragma unroll
        for (int j = 0; j < 4; ++j) {
            f16x2 th = af.h[j] + bb.h[j];
            f16x2 uh = __builtin_elementwise_max(th, th * c02);
            p = __builtin_amdgcn_fdot2(uh, at_h[j], p, false);
        }
#pragma unroll
        for (int off = 1; off < 16; off <<= 1) p += __shfl_xor(p, off);
        float e = __expf(p);
        s += e;
#pragma unroll
        for (int j = 0; j < 4; ++j) {
            a[2*j]   += e * (float)af.h[j].x;
            a[2*j+1] += e * (float)af.h[j].y;
        }
    }
    s += __shfl_xor(s, 16); s += __shfl_xor(s, 32);
#pragma unroll
    for (int j = 0; j < 8; ++j) { a[j] += __shfl_xor(a[j], 16); a[j] += __shfl_xor(a[j], 32); }

    if (g == 0) {
        float rs = 1.f / s;
        float o[8];
#pragma unroll
        for (int j = 0; j < 8; ++j) o[j] = elu(a[j] * rs + bias[c0 + j]);
        size_t ob = (size_t)v * D2 + c0;
        *(float4*)(out + ob)     = make_float4(o[0], o[1], o[2], o[3]);
        *(float4*)(out + ob + 4) = make_float4(o[4], o[5], o[6], o[7]);
    }
}

// ---------- mean pool: one block per graph, inline boundary search, no atomics ----------
__global__ void pool2_k(const int* __restrict__ batch, const float* __restrict__ h,
                        float* __restrict__ out, int N)
{
    __shared__ float part[D2];
    int g = blockIdx.x;
    int t = threadIdx.x;
    int c = t & 127, half = t >> 7;
    int lo = 0, hi = N;
    while (lo < hi) { int m = (lo + hi) >> 1; if (batch[m] < g) lo = m + 1; else hi = m; }
    int lo2 = lo, hi2 = N;
    while (lo2 < hi2) { int m = (lo2 + hi2) >> 1; if (batch[m] < g + 1) lo2 = m + 1; else hi2 = m; }
    float acc = 0.f;
    for (int v = lo + half; v < lo2; v += 2)
        acc += h[(size_t)v * D2 + c];
    if (half == 1) part[c] = acc;
    __syncthreads();
    if (half == 0)
        out[(size_t)g * D2 + c] = (acc + part[c]) / fmaxf((float)(lo2 - lo), 1.f);
}

extern "C" void kernel_launch(void* const* d_in, const int* in_sizes, int n_in,
                              void* d_out, int out_size, void* d_ws, size_t ws_size,
                              hipStream_t stream)
{
    const float* x    = (const float*)d_in[0];
    const int*   ei   = (const int*)d_in[1];
    const int*   batch= (const int*)d_in[2];
    const float* Wl1  = (const float*)d_in[3];
    const float* bl1  = (const float*)d_in[4];
    const float* Wr1  = (const float*)d_in[5];
    const float* br1  = (const float*)d_in[6];
    const float* att1 = (const float*)d_in[7];
    const float* bias1= (const float*)d_in[8];
    const float* Wl2  = (const float*)d_in[9];
    const float* bl2  = (const float*)d_in[10];
    const float* Wr2  = (const float*)d_in[11];
    const float* br2  = (const float*)d_in[12];
    const float* att2 = (const float*)d_in[13];
    const float* bias2= (const float*)d_in[14];
    float* out = (float*)d_out;

    int N    = in_sizes[2];          // batch vector length = nodes
    int E    = in_sizes[1] / 2;      // directed edges (before self-loops)
    int Etot = E + N;
    int G    = out_size / D2;

    char* ws = (char*)d_ws;
    size_t off = 0;
    auto alloc = [&](size_t bytes) -> void* {
        void* p = ws + off;
        off = (off + bytes + 255) & ~(size_t)255;
        return p;
    };
    __half*   xl1h   = (__half*)alloc((size_t)N * HD1 * 2);
    __half*   xr1h   = (__half*)alloc((size_t)N * HD1 * 2);
    __half*   h1h    = (__half*)alloc((size_t)N * HD1 * 2);
    __half*   xl2h   = (__half*)alloc((size_t)N * D2 * 2);
    __half*   xr2h   = (__half*)alloc((size_t)N * D2 * 2);
    float*    h2     = (float*)alloc((size_t)N * D2 * 4);
    unsigned* Wt1    = (unsigned*)alloc((size_t)1024 * KP1 * 4);
    unsigned* Wt2    = (unsigned*)alloc((size_t)256 * 256 * 4);
    int*      counts = (int*)alloc((size_t)(N + 1) * 4);
    int*      offs   = (int*)alloc((size_t)(N + 1) * 4);
    int*      row_ptr= (int*)alloc((size_t)(N + 1) * 4);
    int*      csr_src= (int*)alloc((size_t)Etot * 4);

    int wtot = 1024 * KP1 + 256 * 256;
    int nWB  = (wtot + 255) / 256;
    int nCB  = (Etot + 255) / 256;
    (void)hipMemsetAsync(counts, 0, (size_t)(N + 1) * 4, stream);
    prep_k<<<nWB + nCB, 256, 0, stream>>>(Wl1, Wr1, Wl2, Wr2, Wt1, Wt2, ei, E, Etot, counts, nWB);
    gemm1_k<<<(N + 15) / 16, 256, 0, stream>>>(x, Wt1, bl1, br1, xl1h, xr1h, N);
    scan_k<<<1, 1024, 0, stream>>>(counts, row_ptr, offs, N);
    scatter_k<<<(Etot + 255) / 256, 256, 0, stream>>>(ei, E, Etot, offs, csr_src);
    fused1_k<<<N, 256, 0, stream>>>(row_ptr, csr_src, xl1h, xr1h, att1, bias1, h1h);
    gemm2_k<<<(N + 15) / 16, 256, 0, stream>>>(h1h, Wt2, bl2, br2, xl2h, xr2h, N);
    fused2_k<<<(N + 3) / 4, 256, 0, stream>>>(row_ptr, csr_src, xl2h, xr2h, att2, bias2, h2, N);
    pool2_k<<<G, 256, 0, stream>>>(batch, h2, out, N);
}